// Round 11
// baseline (377.322 us; speedup 1.0000x reference)
//
#include <hip/hip_runtime.h>
#include <math.h>

#define N_NODES 100000
#define N_EDGES 1600000
#define DIM_IN  256
#define DIM_H   64
#define DIM_C   47
#define DIM_CP  48                            // padded h2 row stride (192B aligned)
#define SCAN_CHUNK 1024                       // elems per scan block (256 thr x 4)
#define NBLK_SCAN ((N_NODES + SCAN_CHUNK - 1) / SCAN_CHUNK)   // 98
#define NB       8                            // dst buckets (one per XCD)
#define BUCKET_W 12500                        // nodes per bucket
#define BCAP     204000                       // per-bucket capacity
#define CHUNK_P1 1024                         // edges per pass-1 block (4/thread)
#define BPB      128                          // pass-2 blocks per bucket
#define HBPB     64                           // histogram blocks per bucket

typedef __attribute__((ext_vector_type(8))) short bf16x8;
typedef __attribute__((ext_vector_type(4))) float f32x4;

// RNE float -> bf16 bits
static __device__ __forceinline__ short f2bf(float f) {
  unsigned u = __builtin_bit_cast(unsigned, f);
  u += 0x7FFFu + ((u >> 16) & 1u);
  return (short)(u >> 16);
}

// ---------- zero int buffers ----------
__global__ __launch_bounds__(256) void k_zero(int* __restrict__ cnt,
                                              int* __restrict__ cursor,
                                              int* __restrict__ bucket_cur) {
  int i = blockIdx.x * 256 + threadIdx.x;
  if (i < N_NODES) { cnt[i] = 0; cursor[i] = 0; }
  if (i < NB) bucket_cur[i] = 0;
}

// ---------- pass 1: octant binning (atomic-free on cnt; R10: the fused
// cnt histogram caused 56MB of cross-XCD atomic writeback; moved to k_histb) ----
__global__ __launch_bounds__(256) void k_bin(const int* __restrict__ src,
                                             const int* __restrict__ dst,
                                             int* __restrict__ bucket_cur,
                                             unsigned* __restrict__ bucket_buf) {
  __shared__ int lcnt[NB], lbase[NB], lcur[NB];
  if (threadIdx.x < NB) lcnt[threadIdx.x] = 0;
  __syncthreads();
  const int base = blockIdx.x * CHUNK_P1 + threadIdx.x;
  int dreg[4], sreg[4];
#pragma unroll
  for (int it = 0; it < 4; ++it) {
    int e = base + it * 256;
    int d = -1, s = 0;
    if (e < N_EDGES) { d = dst[e]; s = src[e]; }
    dreg[it] = d; sreg[it] = s;
    if (d >= 0) atomicAdd(&lcnt[d / BUCKET_W], 1);
  }
  __syncthreads();
  if (threadIdx.x < NB) {
    lbase[threadIdx.x] = atomicAdd(&bucket_cur[threadIdx.x], lcnt[threadIdx.x]);
    lcur[threadIdx.x] = 0;
  }
  __syncthreads();
#pragma unroll
  for (int it = 0; it < 4; ++it) {
    int d = dreg[it];
    if (d >= 0) {
      int b = d / BUCKET_W;
      int r = atomicAdd(&lcur[b], 1);
      unsigned pack = ((unsigned)(d - b * BUCKET_W) << 17) | (unsigned)sreg[it];
      bucket_buf[(size_t)b * BCAP + lbase[b] + r] = pack;
    }
  }
}

// ---------- degree histogram from bucketed edges: bucket = blockIdx&7 so each
// 50KB cnt window is hit by one XCD only (no cross-XCD line bouncing) ----------
__global__ __launch_bounds__(256) void k_histb(const unsigned* __restrict__ bucket_buf,
                                               const int* __restrict__ bucket_cnt,
                                               int* __restrict__ cnt) {
  const int b   = blockIdx.x & (NB - 1);
  const int sub = blockIdx.x >> 3;
  const int n_b = bucket_cnt[b];
  const unsigned* buf = bucket_buf + (size_t)b * BCAP;
  int* cnt_b = cnt + b * BUCKET_W;
  for (int i = sub * 256 + (int)threadIdx.x; i < n_b; i += HBPB * 256)
    atomicAdd(&cnt_b[buf[i] >> 17], 1);
}

// ---------- dinv = rsqrt(deg+1) ----------
__global__ __launch_bounds__(256) void k_dinv(const int* __restrict__ cnt,
                                              float* __restrict__ dinv) {
  int i = blockIdx.x * 256 + threadIdx.x;
  if (i < N_NODES) dinv[i] = rsqrtf((float)cnt[i] + 1.0f);
}

// ---------- pad W2 (64x47) into W2p (64x48) ----------
__global__ __launch_bounds__(256) void k_padW2(const float* __restrict__ W2,
                                               float* __restrict__ W2p) {
  int i = blockIdx.x * 256 + threadIdx.x;
  if (i >= DIM_H * DIM_CP) return;
  int k = i / DIM_CP, j = i % DIM_CP;
  W2p[i] = (j < DIM_C) ? W2[k * DIM_C + j] : 0.f;
}

// ---------- pre-swizzle W1 into per-lane MFMA B-fragment order ----------
__global__ __launch_bounds__(256) void k_prepW1(const float* __restrict__ W1,
                                                short* __restrict__ W1f) {
  int i = blockIdx.x * 256 + threadIdx.x;
  if (i >= 4 * 8 * 64 * 8) return;
  int e    = i & 7;
  int lane = (i >> 3) & 63;
  int ks   = (i >> 9) & 7;
  int wv   = i >> 12;
  int col  = wv * 16 + (lane & 15);
  int k    = ks * 32 + (lane >> 4) * 8 + e;
  W1f[i] = f2bf(W1[k * DIM_H + col]);
}

// ---------- exclusive scan of cnt -> row_start ----------
__global__ __launch_bounds__(256) void k_scan_partial(const int* __restrict__ cnt,
                                                      int* __restrict__ row_start,
                                                      int* __restrict__ blk_sums) {
  __shared__ int ls[256];
  const int tid  = threadIdx.x;
  const int base = blockIdx.x * SCAN_CHUNK + tid * 4;
  int c0 = (base + 0 < N_NODES) ? cnt[base + 0] : 0;
  int c1 = (base + 1 < N_NODES) ? cnt[base + 1] : 0;
  int c2 = (base + 2 < N_NODES) ? cnt[base + 2] : 0;
  int c3 = (base + 3 < N_NODES) ? cnt[base + 3] : 0;
  int tsum = c0 + c1 + c2 + c3;
  ls[tid] = tsum;
  __syncthreads();
  for (int off = 1; off < 256; off <<= 1) {
    int v = (tid >= off) ? ls[tid - off] : 0;
    __syncthreads();
    ls[tid] += v;
    __syncthreads();
  }
  int excl = ls[tid] - tsum;
  if (base + 0 < N_NODES) row_start[base + 0] = excl;
  if (base + 1 < N_NODES) row_start[base + 1] = excl + c0;
  if (base + 2 < N_NODES) row_start[base + 2] = excl + c0 + c1;
  if (base + 3 < N_NODES) row_start[base + 3] = excl + c0 + c1 + c2;
  if (tid == 255) blk_sums[blockIdx.x] = ls[255];
}

__global__ __launch_bounds__(128) void k_scan_blk(int* __restrict__ blk_sums) {
  __shared__ int ls[128];
  const int tid = threadIdx.x;
  int v = (tid < NBLK_SCAN) ? blk_sums[tid] : 0;
  ls[tid] = v;
  __syncthreads();
  for (int off = 1; off < 128; off <<= 1) {
    int u = (tid >= off) ? ls[tid - off] : 0;
    __syncthreads();
    ls[tid] += u;
    __syncthreads();
  }
  if (tid < NBLK_SCAN) blk_sums[tid] = ls[tid] - v;
}

__global__ __launch_bounds__(256) void k_scan_add(int* __restrict__ row_start,
                                                  const int* __restrict__ blk_sums) {
  int i = blockIdx.x * 256 + threadIdx.x;
  if (i < N_NODES) row_start[i] += blk_sums[i / SCAN_CHUNK];
}

// ---------- pass 2: per-bucket fine scatter ----------
__global__ __launch_bounds__(256) void k_scatter2(const unsigned* __restrict__ bucket_buf,
                                                  const int* __restrict__ bucket_cnt,
                                                  const int* __restrict__ row_start,
                                                  int* __restrict__ cursor,
                                                  int* __restrict__ sorted_src) {
  const int b   = blockIdx.x & (NB - 1);
  const int sub = blockIdx.x >> 3;
  const int n_b = bucket_cnt[b];
  const unsigned* buf = bucket_buf + (size_t)b * BCAP;
  for (int i = sub * 256 + (int)threadIdx.x; i < n_b; i += BPB * 256) {
    unsigned pack = buf[i];
    int s = (int)(pack & 0x1FFFFu);
    int d = b * BUCKET_W + (int)(pack >> 17);
    int pos = row_start[d] + atomicAdd(&cursor[d], 1);
    sorted_src[pos] = s;
  }
}

// ---------- layer 1 GEMM on matrix cores: h1s = dinv[n] * (x @ W1) ----------
__global__ __launch_bounds__(256) void k_gemm1(const float* __restrict__ x,
                                               const short* __restrict__ W1f,
                                               const float* __restrict__ dinv,
                                               float* __restrict__ h1s) {
  const int lane = threadIdx.x & 63;
  const int wv   = threadIdx.x >> 6;
  const int m16  = lane & 15;
  const int kb   = lane >> 4;                 // 0..3
  const int base_row = blockIdx.x * 16;       // 100000 % 16 == 0
  const float* xp = x + (size_t)(base_row + m16) * DIM_IN + kb * 8;
  const bf16x8* wf = (const bf16x8*)W1f + (size_t)wv * 8 * 64 + lane;

  float4 a[16];
  bf16x8 b[8];
#pragma unroll
  for (int ks = 0; ks < 8; ++ks) {
    a[2 * ks]     = *(const float4*)(xp + ks * 32);
    a[2 * ks + 1] = *(const float4*)(xp + ks * 32 + 4);
    b[ks]         = wf[ks * 64];
  }
  __builtin_amdgcn_sched_barrier(0);   // keep all loads issued up front

  f32x4 c = {0.f, 0.f, 0.f, 0.f};
#pragma unroll
  for (int ks = 0; ks < 8; ++ks) {
    float4 a0 = a[2 * ks], a1 = a[2 * ks + 1];
    bf16x8 af;
    af[0] = f2bf(a0.x); af[1] = f2bf(a0.y); af[2] = f2bf(a0.z); af[3] = f2bf(a0.w);
    af[4] = f2bf(a1.x); af[5] = f2bf(a1.y); af[6] = f2bf(a1.z); af[7] = f2bf(a1.w);
    c = __builtin_amdgcn_mfma_f32_16x16x32_bf16(af, b[ks], c, 0, 0, 0);
  }

  const int j0 = wv * 16 + m16;               // output column
#pragma unroll
  for (int r = 0; r < 4; ++r) {
    int row = base_row + kb * 4 + r;
    h1s[(size_t)row * DIM_H + j0] = c[r] * dinv[row];
  }
}

// ---------- agg1 gather: wave per node, lane = channel, 8-way unrolled ----------
__global__ __launch_bounds__(256) void k_agg1_gather(const float* __restrict__ h1s,
                                                     const float* __restrict__ dinv,
                                                     const float* __restrict__ b1,
                                                     const int* __restrict__ row_start,
                                                     const int* __restrict__ cnt,
                                                     const int* __restrict__ sorted_src,
                                                     float* __restrict__ agg1) {
  int n = blockIdx.x * 4 + (threadIdx.x >> 6);
  int j = threadIdx.x & 63;
  if (n >= N_NODES) return;
  int start = row_start[n];
  int deg   = cnt[n];
  float acc0 = h1s[(size_t)n * DIM_H + j];  // self term
  float acc1 = 0.f, acc2 = 0.f, acc3 = 0.f;
  float acc4 = 0.f, acc5 = 0.f, acc6 = 0.f, acc7 = 0.f;
  int k = 0;
  for (; k + 8 <= deg; k += 8) {
    int s0 = sorted_src[start + k + 0];
    int s1 = sorted_src[start + k + 1];
    int s2 = sorted_src[start + k + 2];
    int s3 = sorted_src[start + k + 3];
    int s4 = sorted_src[start + k + 4];
    int s5 = sorted_src[start + k + 5];
    int s6 = sorted_src[start + k + 6];
    int s7 = sorted_src[start + k + 7];
    acc0 += h1s[(size_t)s0 * DIM_H + j];
    acc1 += h1s[(size_t)s1 * DIM_H + j];
    acc2 += h1s[(size_t)s2 * DIM_H + j];
    acc3 += h1s[(size_t)s3 * DIM_H + j];
    acc4 += h1s[(size_t)s4 * DIM_H + j];
    acc5 += h1s[(size_t)s5 * DIM_H + j];
    acc6 += h1s[(size_t)s6 * DIM_H + j];
    acc7 += h1s[(size_t)s7 * DIM_H + j];
  }
  for (; k + 2 <= deg; k += 2) {
    int s0 = sorted_src[start + k + 0];
    int s1 = sorted_src[start + k + 1];
    acc0 += h1s[(size_t)s0 * DIM_H + j];
    acc1 += h1s[(size_t)s1 * DIM_H + j];
  }
  for (; k < deg; ++k)
    acc0 += h1s[(size_t)sorted_src[start + k] * DIM_H + j];
  float di = dinv[n];
  agg1[(size_t)n * DIM_H + j] =
      di * (((acc0 + acc1) + (acc2 + acc3)) + ((acc4 + acc5) + (acc6 + acc7))) + b1[j];
}

// ---------- layer 2 GEMM + ReLU + dinv pre-scale (fp32, batched x-loads) ----------
__global__ __launch_bounds__(192) void k_gemm2(const float* __restrict__ agg1,
                                               const float* __restrict__ W2p,
                                               const float* __restrict__ dinv,
                                               float* __restrict__ h2p) {
  const int lane = threadIdx.x & 63;
  const int j0   = __builtin_amdgcn_readfirstlane((threadIdx.x >> 6) * 16);
  int row = blockIdx.x * 64 + lane;
  if (row >= N_NODES) row = N_NODES - 1;
  const float4* xr = (const float4*)(agg1 + (size_t)row * DIM_H);

  float4 xv[16];
#pragma unroll
  for (int k4 = 0; k4 < 16; ++k4) xv[k4] = xr[k4];
  __builtin_amdgcn_sched_barrier(0);   // all row loads in flight together

  float acc[16];
#pragma unroll
  for (int j = 0; j < 16; ++j) acc[j] = 0.f;

#pragma unroll
  for (int k4 = 0; k4 < DIM_H / 4; ++k4) {
    float4 v = xv[k4];
    v.x = fmaxf(v.x, 0.f); v.y = fmaxf(v.y, 0.f);
    v.z = fmaxf(v.z, 0.f); v.w = fmaxf(v.w, 0.f);
#pragma unroll
    for (int kk = 0; kk < 4; ++kk) {
      float xk = (kk == 0) ? v.x : (kk == 1) ? v.y : (kk == 2) ? v.z : v.w;
      const float* wrow = W2p + (size_t)(4 * k4 + kk) * DIM_CP + j0;  // uniform -> s_load
#pragma unroll
      for (int j = 0; j < 16; ++j)
        acc[j] = fmaf(xk, wrow[j], acc[j]);
    }
  }

  float di = dinv[row];
  float4* out = (float4*)(h2p + (size_t)row * DIM_CP + j0);
#pragma unroll
  for (int j4 = 0; j4 < 4; ++j4)
    out[j4] = make_float4(di * acc[4 * j4], di * acc[4 * j4 + 1],
                          di * acc[4 * j4 + 2], di * acc[4 * j4 + 3]);
}

// ---------- agg2 gather + fused log_softmax: wave per node, 8-way unrolled ----------
__global__ __launch_bounds__(256) void k_agg2_gather(const float* __restrict__ h2p,
                                                     const float* __restrict__ dinv,
                                                     const float* __restrict__ b2,
                                                     const int* __restrict__ row_start,
                                                     const int* __restrict__ cnt,
                                                     const int* __restrict__ sorted_src,
                                                     float* __restrict__ out) {
  int n = blockIdx.x * 4 + (threadIdx.x >> 6);
  int j = threadIdx.x & 63;
  if (n >= N_NODES) return;
  int jj = (j < DIM_C) ? j : DIM_C;  // lanes >=47 read the zero pad
  int start = row_start[n];
  int deg   = cnt[n];
  float acc0 = h2p[(size_t)n * DIM_CP + jj];  // self term
  float acc1 = 0.f, acc2 = 0.f, acc3 = 0.f;
  float acc4 = 0.f, acc5 = 0.f, acc6 = 0.f, acc7 = 0.f;
  int k = 0;
  for (; k + 8 <= deg; k += 8) {
    int s0 = sorted_src[start + k + 0];
    int s1 = sorted_src[start + k + 1];
    int s2 = sorted_src[start + k + 2];
    int s3 = sorted_src[start + k + 3];
    int s4 = sorted_src[start + k + 4];
    int s5 = sorted_src[start + k + 5];
    int s6 = sorted_src[start + k + 6];
    int s7 = sorted_src[start + k + 7];
    acc0 += h2p[(size_t)s0 * DIM_CP + jj];
    acc1 += h2p[(size_t)s1 * DIM_CP + jj];
    acc2 += h2p[(size_t)s2 * DIM_CP + jj];
    acc3 += h2p[(size_t)s3 * DIM_CP + jj];
    acc4 += h2p[(size_t)s4 * DIM_CP + jj];
    acc5 += h2p[(size_t)s5 * DIM_CP + jj];
    acc6 += h2p[(size_t)s6 * DIM_CP + jj];
    acc7 += h2p[(size_t)s7 * DIM_CP + jj];
  }
  for (; k + 2 <= deg; k += 2) {
    int s0 = sorted_src[start + k + 0];
    int s1 = sorted_src[start + k + 1];
    acc0 += h2p[(size_t)s0 * DIM_CP + jj];
    acc1 += h2p[(size_t)s1 * DIM_CP + jj];
  }
  for (; k < deg; ++k)
    acc0 += h2p[(size_t)sorted_src[start + k] * DIM_CP + jj];
  float di = dinv[n];
  float acc = di * (((acc0 + acc1) + (acc2 + acc3)) + ((acc4 + acc5) + (acc6 + acc7)))
            + ((j < DIM_C) ? b2[jj] : 0.f);

  // fused log_softmax over the 47 classes
  float v = (j < DIM_C) ? acc : -INFINITY;
  float m = v;
  for (int o = 32; o; o >>= 1) m = fmaxf(m, __shfl_xor(m, o));
  float ex = (j < DIM_C) ? __expf(v - m) : 0.0f;
  float s = ex;
  for (int o = 32; o; o >>= 1) s += __shfl_xor(s, o);
  if (j < DIM_C) out[(size_t)n * DIM_C + j] = v - m - __logf(s);
}

extern "C" void kernel_launch(void* const* d_in, const int* in_sizes, int n_in,
                              void* d_out, int out_size, void* d_ws, size_t ws_size,
                              hipStream_t stream) {
  const float* x  = (const float*)d_in[0];
  const float* W1 = (const float*)d_in[1];
  const float* b1 = (const float*)d_in[2];
  const float* W2 = (const float*)d_in[3];
  const float* b2 = (const float*)d_in[4];
  const int*   ei = (const int*)d_in[5];
  const int* src = ei;
  const int* dst = ei + N_EDGES;
  float* out = (float*)d_out;

  float* ws   = (float*)d_ws;
  float* dinv = ws;                                   // N
  float* W2p  = dinv + N_NODES;                       // 64*48
  short* W1f  = (short*)(W2p + DIM_H * DIM_CP);       // 16384 shorts
  float* h1s  = (float*)(W1f + 4 * 8 * 64 * 8);       // N*64 (reused for h2p, N*48)
  float* agg1 = h1s + (size_t)N_NODES * DIM_H;        // N*64
  float* h2p  = h1s;                                  // alias: h1s dead after agg1_gather
  int* ibuf        = (int*)(agg1 + (size_t)N_NODES * DIM_H);
  int* cnt         = ibuf;                            // N
  int* cursor      = cnt + N_NODES;                   // N
  int* row_start   = cursor + N_NODES;                // N
  int* blk_sums    = row_start + N_NODES;             // 128
  int* bucket_cur  = blk_sums + 128;                  // 8 (+pad)
  int* sorted_src  = bucket_cur + 64;                 // E
  unsigned* bucket_buf = (unsigned*)(sorted_src + N_EDGES);  // NB*BCAP

  const int nblk_n  = (N_NODES + 255) / 256;
  const int nblk_nw = (N_NODES + 3) / 4;              // wave-per-node gathers
  const int nblk_g1 = N_NODES / 16;                   // 6250 MFMA tiles
  const int nblk_g2 = (N_NODES + 63) / 64;            // fp32 gemm2 tiles
  const int nblk_p1 = (N_EDGES + CHUNK_P1 - 1) / CHUNK_P1;   // 1563

  // CSR build (two-pass bucket sort + XCD-local histogram) + weight prep
  k_zero<<<nblk_n, 256, 0, stream>>>(cnt, cursor, bucket_cur);
  k_bin<<<nblk_p1, 256, 0, stream>>>(src, dst, bucket_cur, bucket_buf);
  k_histb<<<NB * HBPB, 256, 0, stream>>>(bucket_buf, bucket_cur, cnt);
  k_dinv<<<nblk_n, 256, 0, stream>>>(cnt, dinv);
  k_padW2<<<(DIM_H * DIM_CP + 255) / 256, 256, 0, stream>>>(W2, W2p);
  k_prepW1<<<64, 256, 0, stream>>>(W1, W1f);
  k_scan_partial<<<NBLK_SCAN, 256, 0, stream>>>(cnt, row_start, blk_sums);
  k_scan_blk<<<1, 128, 0, stream>>>(blk_sums);
  k_scan_add<<<nblk_n, 256, 0, stream>>>(row_start, blk_sums);
  k_scatter2<<<NB * BPB, 256, 0, stream>>>(bucket_buf, bucket_cur, row_start, cursor, sorted_src);

  // layer 1 (MFMA)
  k_gemm1<<<nblk_g1, 256, 0, stream>>>(x, W1f, dinv, h1s);
  k_agg1_gather<<<nblk_nw, 256, 0, stream>>>(h1s, dinv, b1, row_start, cnt, sorted_src, agg1);

  // layer 2 (+ fused log_softmax)
  k_gemm2<<<nblk_g2, 192, 0, stream>>>(agg1, W2p, dinv, h2p);
  k_agg2_gather<<<nblk_nw, 256, 0, stream>>>(h2p, dinv, b2, row_start, cnt, sorted_src, out);
}

// Round 12
// 264.623 us; speedup vs baseline: 1.4259x; 1.4259x over previous
//
#include <hip/hip_runtime.h>
#include <math.h>

#define N_NODES 100000
#define N_EDGES 1600000
#define DIM_IN  256
#define DIM_H   64
#define DIM_C   47
#define DIM_CP  48                            // padded h2 row stride (192B aligned)
#define NB       8                            // coarse dst buckets
#define BUCKET_W 12500                        // nodes per bucket
#define BCAP     204000                       // per-bucket capacity (9.5 sigma)
#define CHUNK_P1 1024                         // edges per pass-1 block (4/thread)
#define SEG_P2   2048                         // bucket-buf segment per pass-2a block
#define NSEG_P2  100                          // segments per bucket (100*2048 >= BCAP)
#define CHUNK_NODES 250                       // nodes per fine chunk
#define NCHUNK   400                          // N_NODES / 250
#define CCAP     4608                         // per-chunk edge capacity (mean 4000 + 9.6 sigma)

typedef __attribute__((ext_vector_type(8))) short bf16x8;
typedef __attribute__((ext_vector_type(4))) float f32x4;

// RNE float -> bf16 bits
static __device__ __forceinline__ short f2bf(float f) {
  unsigned u = __builtin_bit_cast(unsigned, f);
  u += 0x7FFFu + ((u >> 16) & 1u);
  return (short)(u >> 16);
}

// ---------- zero the 408 counters ----------
__global__ __launch_bounds__(512) void k_zero(int* __restrict__ bucket_cur,
                                              int* __restrict__ chunk_cur) {
  if (threadIdx.x < NB) bucket_cur[threadIdx.x] = 0;
  if (threadIdx.x < NCHUNK) chunk_cur[threadIdx.x] = 0;
}

// ---------- pass 1: coarse octant binning (dense reservation writes) ----------
__global__ __launch_bounds__(256) void k_bin(const int* __restrict__ src,
                                             const int* __restrict__ dst,
                                             int* __restrict__ bucket_cur,
                                             unsigned* __restrict__ bucket_buf) {
  __shared__ int lcnt[NB], lbase[NB], lcur[NB];
  if (threadIdx.x < NB) lcnt[threadIdx.x] = 0;
  __syncthreads();
  const int base = blockIdx.x * CHUNK_P1 + threadIdx.x;
  int dreg[4], sreg[4];
#pragma unroll
  for (int it = 0; it < 4; ++it) {
    int e = base + it * 256;
    int d = -1, s = 0;
    if (e < N_EDGES) { d = dst[e]; s = src[e]; }
    dreg[it] = d; sreg[it] = s;
    if (d >= 0) atomicAdd(&lcnt[d / BUCKET_W], 1);
  }
  __syncthreads();
  if (threadIdx.x < NB) {
    lbase[threadIdx.x] = atomicAdd(&bucket_cur[threadIdx.x], lcnt[threadIdx.x]);
    lcur[threadIdx.x] = 0;
  }
  __syncthreads();
#pragma unroll
  for (int it = 0; it < 4; ++it) {
    int d = dreg[it];
    if (d >= 0) {
      int b = d / BUCKET_W;
      int r = atomicAdd(&lcur[b], 1);
      unsigned pack = ((unsigned)(d - b * BUCKET_W) << 17) | (unsigned)sreg[it];
      bucket_buf[(size_t)b * BCAP + lbase[b] + r] = pack;
    }
  }
}

// ---------- pass 2a: bucket -> 50 fine chunks (dense reservation writes) ----------
__global__ __launch_bounds__(256) void k_bin2(const unsigned* __restrict__ bucket_buf,
                                              const int* __restrict__ bucket_cnt,
                                              int* __restrict__ chunk_cur,
                                              unsigned* __restrict__ chunk_buf) {
  const int b   = blockIdx.x / NSEG_P2;
  const int seg = blockIdx.x % NSEG_P2;
  const int n_b = bucket_cnt[b];
  const int s0  = seg * SEG_P2;
  const int s1  = (n_b < s0 + SEG_P2) ? n_b : (s0 + SEG_P2);
  __shared__ int lcnt[50], lbase[50], lcur[50];
  if (threadIdx.x < 50) lcnt[threadIdx.x] = 0;
  __syncthreads();
  unsigned preg[8]; int creg[8];
#pragma unroll
  for (int it = 0; it < 8; ++it) {
    int i = s0 + it * 256 + (int)threadIdx.x;
    unsigned p = 0; int cl = -1;
    if (i < s1) { p = bucket_buf[(size_t)b * BCAP + i]; cl = (int)(p >> 17) / CHUNK_NODES; atomicAdd(&lcnt[cl], 1); }
    preg[it] = p; creg[it] = cl;
  }
  __syncthreads();
  if (threadIdx.x < 50) {
    lbase[threadIdx.x] = atomicAdd(&chunk_cur[b * 50 + threadIdx.x], lcnt[threadIdx.x]);
    lcur[threadIdx.x] = 0;
  }
  __syncthreads();
#pragma unroll
  for (int it = 0; it < 8; ++it) {
    int cl = creg[it];
    if (cl >= 0) {
      unsigned p = preg[it];
      int dl = (int)(p >> 17) - cl * CHUNK_NODES;   // 0..249 within chunk
      int r = atomicAdd(&lcur[cl], 1);
      chunk_buf[(size_t)(b * 50 + cl) * CCAP + lbase[cl] + r] =
          ((unsigned)dl << 17) | (p & 0x1FFFFu);
    }
  }
}

// ---------- exclusive scan of the 400 chunk counts ----------
__global__ __launch_bounds__(512) void k_scan_chunks(const int* __restrict__ chunk_cur,
                                                     int* __restrict__ chunk_base) {
  __shared__ int ls[512];
  const int tid = threadIdx.x;
  int v = (tid < NCHUNK) ? chunk_cur[tid] : 0;
  ls[tid] = v;
  __syncthreads();
  for (int off = 1; off < 512; off <<= 1) {
    int u = (tid >= off) ? ls[tid - off] : 0;
    __syncthreads();
    ls[tid] += u;
    __syncthreads();
  }
  if (tid < NCHUNK) chunk_base[tid] = ls[tid] - v;
}

// ---------- pass 2b: per-chunk LDS counting sort; sequential global writes ----------
// Produces sorted_src (dst-sorted CSR adjacency), cnt (in-degree), row_start.
__global__ __launch_bounds__(256) void k_sort_chunk(const unsigned* __restrict__ chunk_buf,
                                                    const int* __restrict__ chunk_cur,
                                                    const int* __restrict__ chunk_base,
                                                    int* __restrict__ cnt,
                                                    int* __restrict__ row_start,
                                                    int* __restrict__ sorted_src) {
  const int c    = blockIdx.x;
  const int n_c  = chunk_cur[c];
  const int base = chunk_base[c];
  const unsigned* buf = chunk_buf + (size_t)c * CCAP;
  __shared__ int cntA[256], exclA[256], curA[256];
  __shared__ int sortedL[CCAP];
  const int tid = threadIdx.x;
  cntA[tid] = 0; curA[tid] = 0;
  __syncthreads();
  for (int i = tid; i < n_c; i += 256) atomicAdd(&cntA[buf[i] >> 17], 1);
  __syncthreads();
  int myc = cntA[tid];
  exclA[tid] = myc;
  __syncthreads();
  for (int off = 1; off < 256; off <<= 1) {
    int u = (tid >= off) ? exclA[tid - off] : 0;
    __syncthreads();
    exclA[tid] += u;
    __syncthreads();
  }
  int excl = exclA[tid] - myc;
  if (tid < CHUNK_NODES) {
    int n = c * CHUNK_NODES + tid;
    cnt[n] = myc;
    row_start[n] = base + excl;
  }
  __syncthreads();
  exclA[tid] = excl;
  __syncthreads();
  for (int i = tid; i < n_c; i += 256) {
    unsigned p = buf[i];
    int dl = (int)(p >> 17);
    int pos = exclA[dl] + atomicAdd(&curA[dl], 1);
    sortedL[pos] = (int)(p & 0x1FFFFu);
  }
  __syncthreads();
  for (int i = tid; i < n_c; i += 256) sorted_src[base + i] = sortedL[i];
}

// ---------- dinv = rsqrt(deg+1) ----------
__global__ __launch_bounds__(256) void k_dinv(const int* __restrict__ cnt,
                                              float* __restrict__ dinv) {
  int i = blockIdx.x * 256 + threadIdx.x;
  if (i < N_NODES) dinv[i] = rsqrtf((float)cnt[i] + 1.0f);
}

// ---------- pad W2 (64x47) into W2p (64x48) ----------
__global__ __launch_bounds__(256) void k_padW2(const float* __restrict__ W2,
                                               float* __restrict__ W2p) {
  int i = blockIdx.x * 256 + threadIdx.x;
  if (i >= DIM_H * DIM_CP) return;
  int k = i / DIM_CP, j = i % DIM_CP;
  W2p[i] = (j < DIM_C) ? W2[k * DIM_C + j] : 0.f;
}

// ---------- pre-swizzle W1 into per-lane MFMA B-fragment order ----------
__global__ __launch_bounds__(256) void k_prepW1(const float* __restrict__ W1,
                                                short* __restrict__ W1f) {
  int i = blockIdx.x * 256 + threadIdx.x;
  if (i >= 4 * 8 * 64 * 8) return;
  int e    = i & 7;
  int lane = (i >> 3) & 63;
  int ks   = (i >> 9) & 7;
  int wv   = i >> 12;
  int col  = wv * 16 + (lane & 15);
  int k    = ks * 32 + (lane >> 4) * 8 + e;
  W1f[i] = f2bf(W1[k * DIM_H + col]);
}

// ---------- layer 1 GEMM on matrix cores: h1s = dinv[n] * (x @ W1) ----------
__global__ __launch_bounds__(256) void k_gemm1(const float* __restrict__ x,
                                               const short* __restrict__ W1f,
                                               const float* __restrict__ dinv,
                                               float* __restrict__ h1s) {
  const int lane = threadIdx.x & 63;
  const int wv   = threadIdx.x >> 6;
  const int m16  = lane & 15;
  const int kb   = lane >> 4;                 // 0..3
  const int base_row = blockIdx.x * 16;       // 100000 % 16 == 0
  const float* xp = x + (size_t)(base_row + m16) * DIM_IN + kb * 8;
  const bf16x8* wf = (const bf16x8*)W1f + (size_t)wv * 8 * 64 + lane;

  float4 a[16];
  bf16x8 b[8];
#pragma unroll
  for (int ks = 0; ks < 8; ++ks) {
    a[2 * ks]     = *(const float4*)(xp + ks * 32);
    a[2 * ks + 1] = *(const float4*)(xp + ks * 32 + 4);
    b[ks]         = wf[ks * 64];
  }
  __builtin_amdgcn_sched_barrier(0);   // keep all loads issued up front

  f32x4 c = {0.f, 0.f, 0.f, 0.f};
#pragma unroll
  for (int ks = 0; ks < 8; ++ks) {
    float4 a0 = a[2 * ks], a1 = a[2 * ks + 1];
    bf16x8 af;
    af[0] = f2bf(a0.x); af[1] = f2bf(a0.y); af[2] = f2bf(a0.z); af[3] = f2bf(a0.w);
    af[4] = f2bf(a1.x); af[5] = f2bf(a1.y); af[6] = f2bf(a1.z); af[7] = f2bf(a1.w);
    c = __builtin_amdgcn_mfma_f32_16x16x32_bf16(af, b[ks], c, 0, 0, 0);
  }

  const int j0 = wv * 16 + m16;               // output column
#pragma unroll
  for (int r = 0; r < 4; ++r) {
    int row = base_row + kb * 4 + r;
    h1s[(size_t)row * DIM_H + j0] = c[r] * dinv[row];
  }
}

// ---------- agg1 gather: wave per node, lane = channel, 8-way unrolled ----------
__global__ __launch_bounds__(256) void k_agg1_gather(const float* __restrict__ h1s,
                                                     const float* __restrict__ dinv,
                                                     const float* __restrict__ b1,
                                                     const int* __restrict__ row_start,
                                                     const int* __restrict__ cnt,
                                                     const int* __restrict__ sorted_src,
                                                     float* __restrict__ agg1) {
  int n = blockIdx.x * 4 + (threadIdx.x >> 6);
  int j = threadIdx.x & 63;
  if (n >= N_NODES) return;
  int start = row_start[n];
  int deg   = cnt[n];
  float acc0 = h1s[(size_t)n * DIM_H + j];  // self term
  float acc1 = 0.f, acc2 = 0.f, acc3 = 0.f;
  float acc4 = 0.f, acc5 = 0.f, acc6 = 0.f, acc7 = 0.f;
  int k = 0;
  for (; k + 8 <= deg; k += 8) {
    int s0 = sorted_src[start + k + 0];
    int s1 = sorted_src[start + k + 1];
    int s2 = sorted_src[start + k + 2];
    int s3 = sorted_src[start + k + 3];
    int s4 = sorted_src[start + k + 4];
    int s5 = sorted_src[start + k + 5];
    int s6 = sorted_src[start + k + 6];
    int s7 = sorted_src[start + k + 7];
    acc0 += h1s[(size_t)s0 * DIM_H + j];
    acc1 += h1s[(size_t)s1 * DIM_H + j];
    acc2 += h1s[(size_t)s2 * DIM_H + j];
    acc3 += h1s[(size_t)s3 * DIM_H + j];
    acc4 += h1s[(size_t)s4 * DIM_H + j];
    acc5 += h1s[(size_t)s5 * DIM_H + j];
    acc6 += h1s[(size_t)s6 * DIM_H + j];
    acc7 += h1s[(size_t)s7 * DIM_H + j];
  }
  for (; k + 2 <= deg; k += 2) {
    int s0 = sorted_src[start + k + 0];
    int s1 = sorted_src[start + k + 1];
    acc0 += h1s[(size_t)s0 * DIM_H + j];
    acc1 += h1s[(size_t)s1 * DIM_H + j];
  }
  for (; k < deg; ++k)
    acc0 += h1s[(size_t)sorted_src[start + k] * DIM_H + j];
  float di = dinv[n];
  agg1[(size_t)n * DIM_H + j] =
      di * (((acc0 + acc1) + (acc2 + acc3)) + ((acc4 + acc5) + (acc6 + acc7))) + b1[j];
}

// ---------- layer 2 GEMM + ReLU + dinv pre-scale (fp32, batched x-loads) ----------
__global__ __launch_bounds__(192) void k_gemm2(const float* __restrict__ agg1,
                                               const float* __restrict__ W2p,
                                               const float* __restrict__ dinv,
                                               float* __restrict__ h2p) {
  const int lane = threadIdx.x & 63;
  const int j0   = __builtin_amdgcn_readfirstlane((threadIdx.x >> 6) * 16);
  int row = blockIdx.x * 64 + lane;
  if (row >= N_NODES) row = N_NODES - 1;
  const float4* xr = (const float4*)(agg1 + (size_t)row * DIM_H);

  float4 xv[16];
#pragma unroll
  for (int k4 = 0; k4 < 16; ++k4) xv[k4] = xr[k4];
  __builtin_amdgcn_sched_barrier(0);   // all row loads in flight together

  float acc[16];
#pragma unroll
  for (int j = 0; j < 16; ++j) acc[j] = 0.f;

#pragma unroll
  for (int k4 = 0; k4 < DIM_H / 4; ++k4) {
    float4 v = xv[k4];
    v.x = fmaxf(v.x, 0.f); v.y = fmaxf(v.y, 0.f);
    v.z = fmaxf(v.z, 0.f); v.w = fmaxf(v.w, 0.f);
#pragma unroll
    for (int kk = 0; kk < 4; ++kk) {
      float xk = (kk == 0) ? v.x : (kk == 1) ? v.y : (kk == 2) ? v.z : v.w;
      const float* wrow = W2p + (size_t)(4 * k4 + kk) * DIM_CP + j0;  // uniform -> s_load
#pragma unroll
      for (int j = 0; j < 16; ++j)
        acc[j] = fmaf(xk, wrow[j], acc[j]);
    }
  }

  float di = dinv[row];
  float4* out = (float4*)(h2p + (size_t)row * DIM_CP + j0);
#pragma unroll
  for (int j4 = 0; j4 < 4; ++j4)
    out[j4] = make_float4(di * acc[4 * j4], di * acc[4 * j4 + 1],
                          di * acc[4 * j4 + 2], di * acc[4 * j4 + 3]);
}

// ---------- agg2 gather + fused log_softmax: wave per node, 8-way unrolled ----------
__global__ __launch_bounds__(256) void k_agg2_gather(const float* __restrict__ h2p,
                                                     const float* __restrict__ dinv,
                                                     const float* __restrict__ b2,
                                                     const int* __restrict__ row_start,
                                                     const int* __restrict__ cnt,
                                                     const int* __restrict__ sorted_src,
                                                     float* __restrict__ out) {
  int n = blockIdx.x * 4 + (threadIdx.x >> 6);
  int j = threadIdx.x & 63;
  if (n >= N_NODES) return;
  int jj = (j < DIM_C) ? j : DIM_C;  // lanes >=47 read the zero pad
  int start = row_start[n];
  int deg   = cnt[n];
  float acc0 = h2p[(size_t)n * DIM_CP + jj];  // self term
  float acc1 = 0.f, acc2 = 0.f, acc3 = 0.f;
  float acc4 = 0.f, acc5 = 0.f, acc6 = 0.f, acc7 = 0.f;
  int k = 0;
  for (; k + 8 <= deg; k += 8) {
    int s0 = sorted_src[start + k + 0];
    int s1 = sorted_src[start + k + 1];
    int s2 = sorted_src[start + k + 2];
    int s3 = sorted_src[start + k + 3];
    int s4 = sorted_src[start + k + 4];
    int s5 = sorted_src[start + k + 5];
    int s6 = sorted_src[start + k + 6];
    int s7 = sorted_src[start + k + 7];
    acc0 += h2p[(size_t)s0 * DIM_CP + jj];
    acc1 += h2p[(size_t)s1 * DIM_CP + jj];
    acc2 += h2p[(size_t)s2 * DIM_CP + jj];
    acc3 += h2p[(size_t)s3 * DIM_CP + jj];
    acc4 += h2p[(size_t)s4 * DIM_CP + jj];
    acc5 += h2p[(size_t)s5 * DIM_CP + jj];
    acc6 += h2p[(size_t)s6 * DIM_CP + jj];
    acc7 += h2p[(size_t)s7 * DIM_CP + jj];
  }
  for (; k + 2 <= deg; k += 2) {
    int s0 = sorted_src[start + k + 0];
    int s1 = sorted_src[start + k + 1];
    acc0 += h2p[(size_t)s0 * DIM_CP + jj];
    acc1 += h2p[(size_t)s1 * DIM_CP + jj];
  }
  for (; k < deg; ++k)
    acc0 += h2p[(size_t)sorted_src[start + k] * DIM_CP + jj];
  float di = dinv[n];
  float acc = di * (((acc0 + acc1) + (acc2 + acc3)) + ((acc4 + acc5) + (acc6 + acc7)))
            + ((j < DIM_C) ? b2[jj] : 0.f);

  // fused log_softmax over the 47 classes
  float v = (j < DIM_C) ? acc : -INFINITY;
  float m = v;
  for (int o = 32; o; o >>= 1) m = fmaxf(m, __shfl_xor(m, o));
  float ex = (j < DIM_C) ? __expf(v - m) : 0.0f;
  float s = ex;
  for (int o = 32; o; o >>= 1) s += __shfl_xor(s, o);
  if (j < DIM_C) out[(size_t)n * DIM_C + j] = v - m - __logf(s);
}

extern "C" void kernel_launch(void* const* d_in, const int* in_sizes, int n_in,
                              void* d_out, int out_size, void* d_ws, size_t ws_size,
                              hipStream_t stream) {
  const float* x  = (const float*)d_in[0];
  const float* W1 = (const float*)d_in[1];
  const float* b1 = (const float*)d_in[2];
  const float* W2 = (const float*)d_in[3];
  const float* b2 = (const float*)d_in[4];
  const int*   ei = (const int*)d_in[5];
  const int* src = ei;
  const int* dst = ei + N_EDGES;
  float* out = (float*)d_out;

  float* ws   = (float*)d_ws;
  float* dinv = ws;                                   // N
  float* W2p  = dinv + N_NODES;                       // 64*48
  short* W1f  = (short*)(W2p + DIM_H * DIM_CP);       // 16384 shorts
  float* h1s  = (float*)(W1f + 4 * 8 * 64 * 8);       // N*64 (reused for h2p and chunk_buf)
  float* agg1 = h1s + (size_t)N_NODES * DIM_H;        // N*64
  float* h2p  = h1s;                                  // alias: h1s dead after agg1_gather
  unsigned* chunk_buf = (unsigned*)h1s;               // alias: dead before gemm1 writes h1s
  int* ibuf        = (int*)(agg1 + (size_t)N_NODES * DIM_H);
  int* cnt         = ibuf;                            // N
  int* row_start   = cnt + N_NODES;                   // N
  int* bucket_cur  = row_start + N_NODES;             // 8 (+pad)
  int* chunk_cur   = bucket_cur + 64;                 // 400
  int* chunk_base  = chunk_cur + NCHUNK;              // 400 (+pad)
  int* sorted_src  = chunk_base + NCHUNK + 64;        // E
  unsigned* bucket_buf = (unsigned*)(sorted_src + N_EDGES);  // NB*BCAP

  const int nblk_n  = (N_NODES + 255) / 256;
  const int nblk_nw = (N_NODES + 3) / 4;              // wave-per-node gathers
  const int nblk_g1 = N_NODES / 16;                   // 6250 MFMA tiles
  const int nblk_g2 = (N_NODES + 63) / 64;            // fp32 gemm2 tiles
  const int nblk_p1 = (N_EDGES + CHUNK_P1 - 1) / CHUNK_P1;   // 1563

  // CSR build: coarse bin -> fine bin -> 400-elem scan -> per-chunk LDS sort
  k_zero<<<1, 512, 0, stream>>>(bucket_cur, chunk_cur);
  k_bin<<<nblk_p1, 256, 0, stream>>>(src, dst, bucket_cur, bucket_buf);
  k_bin2<<<NB * NSEG_P2, 256, 0, stream>>>(bucket_buf, bucket_cur, chunk_cur, chunk_buf);
  k_scan_chunks<<<1, 512, 0, stream>>>(chunk_cur, chunk_base);
  k_sort_chunk<<<NCHUNK, 256, 0, stream>>>(chunk_buf, chunk_cur, chunk_base,
                                           cnt, row_start, sorted_src);
  k_dinv<<<nblk_n, 256, 0, stream>>>(cnt, dinv);
  k_padW2<<<(DIM_H * DIM_CP + 255) / 256, 256, 0, stream>>>(W2, W2p);
  k_prepW1<<<64, 256, 0, stream>>>(W1, W1f);

  // layer 1 (MFMA)
  k_gemm1<<<nblk_g1, 256, 0, stream>>>(x, W1f, dinv, h1s);
  k_agg1_gather<<<nblk_nw, 256, 0, stream>>>(h1s, dinv, b1, row_start, cnt, sorted_src, agg1);

  // layer 2 (+ fused log_softmax)
  k_gemm2<<<nblk_g2, 192, 0, stream>>>(agg1, W2p, dinv, h2p);
  k_agg2_gather<<<nblk_nw, 256, 0, stream>>>(h2p, dinv, b2, row_start, cnt, sorted_src, out);
}

// Round 13
// 263.901 us; speedup vs baseline: 1.4298x; 1.0027x over previous
//
#include <hip/hip_runtime.h>
#include <math.h>

#define N_NODES 100000
#define N_EDGES 1600000
#define DIM_IN  256
#define DIM_H   64
#define DIM_C   47
#define DIM_CP  48                            // padded h2 row stride (96B bf16)
#define NB       8                            // coarse dst buckets
#define BUCKET_W 12500                        // nodes per bucket
#define BCAP     204000                       // per-bucket capacity (9.5 sigma)
#define CHUNK_P1 1024                         // edges per pass-1 block (4/thread)
#define SEG_P2   2048                         // bucket-buf segment per pass-2a block
#define NSEG_P2  100                          // segments per bucket
#define CHUNK_NODES 250                       // nodes per fine chunk
#define NCHUNK   400                          // N_NODES / 250
#define CCAP     4608                         // per-chunk edge capacity

typedef __attribute__((ext_vector_type(8))) short bf16x8;
typedef __attribute__((ext_vector_type(4))) float f32x4;

// RNE float -> bf16 bits
static __device__ __forceinline__ unsigned short f2bf(float f) {
  unsigned u = __builtin_bit_cast(unsigned, f);
  u += 0x7FFFu + ((u >> 16) & 1u);
  return (unsigned short)(u >> 16);
}
static __device__ __forceinline__ float bf2f(unsigned short h) {
  unsigned u = ((unsigned)h) << 16;
  return __builtin_bit_cast(float, u);
}

// ---------- zero the counters ----------
__global__ __launch_bounds__(512) void k_zero(int* __restrict__ bucket_cur,
                                              int* __restrict__ chunk_cur) {
  if (threadIdx.x < NB) bucket_cur[threadIdx.x] = 0;
  if (threadIdx.x < NCHUNK) chunk_cur[threadIdx.x] = 0;
}

// ---------- pass 1: coarse octant binning (dense reservation writes) ----------
__global__ __launch_bounds__(256) void k_bin(const int* __restrict__ src,
                                             const int* __restrict__ dst,
                                             int* __restrict__ bucket_cur,
                                             unsigned* __restrict__ bucket_buf) {
  __shared__ int lcnt[NB], lbase[NB], lcur[NB];
  if (threadIdx.x < NB) lcnt[threadIdx.x] = 0;
  __syncthreads();
  const int base = blockIdx.x * CHUNK_P1 + threadIdx.x;
  int dreg[4], sreg[4];
#pragma unroll
  for (int it = 0; it < 4; ++it) {
    int e = base + it * 256;
    int d = -1, s = 0;
    if (e < N_EDGES) { d = dst[e]; s = src[e]; }
    dreg[it] = d; sreg[it] = s;
    if (d >= 0) atomicAdd(&lcnt[d / BUCKET_W], 1);
  }
  __syncthreads();
  if (threadIdx.x < NB) {
    lbase[threadIdx.x] = atomicAdd(&bucket_cur[threadIdx.x], lcnt[threadIdx.x]);
    lcur[threadIdx.x] = 0;
  }
  __syncthreads();
#pragma unroll
  for (int it = 0; it < 4; ++it) {
    int d = dreg[it];
    if (d >= 0) {
      int b = d / BUCKET_W;
      int r = atomicAdd(&lcur[b], 1);
      unsigned pack = ((unsigned)(d - b * BUCKET_W) << 17) | (unsigned)sreg[it];
      bucket_buf[(size_t)b * BCAP + lbase[b] + r] = pack;
    }
  }
}

// ---------- pass 2a: bucket -> 50 fine chunks (dense reservation writes) ----------
__global__ __launch_bounds__(256) void k_bin2(const unsigned* __restrict__ bucket_buf,
                                              const int* __restrict__ bucket_cnt,
                                              int* __restrict__ chunk_cur,
                                              unsigned* __restrict__ chunk_buf) {
  const int b   = blockIdx.x / NSEG_P2;
  const int seg = blockIdx.x % NSEG_P2;
  const int n_b = bucket_cnt[b];
  const int s0  = seg * SEG_P2;
  const int s1  = (n_b < s0 + SEG_P2) ? n_b : (s0 + SEG_P2);
  __shared__ int lcnt[50], lbase[50], lcur[50];
  if (threadIdx.x < 50) lcnt[threadIdx.x] = 0;
  __syncthreads();
  unsigned preg[8]; int creg[8];
#pragma unroll
  for (int it = 0; it < 8; ++it) {
    int i = s0 + it * 256 + (int)threadIdx.x;
    unsigned p = 0; int cl = -1;
    if (i < s1) { p = bucket_buf[(size_t)b * BCAP + i]; cl = (int)(p >> 17) / CHUNK_NODES; atomicAdd(&lcnt[cl], 1); }
    preg[it] = p; creg[it] = cl;
  }
  __syncthreads();
  if (threadIdx.x < 50) {
    lbase[threadIdx.x] = atomicAdd(&chunk_cur[b * 50 + threadIdx.x], lcnt[threadIdx.x]);
    lcur[threadIdx.x] = 0;
  }
  __syncthreads();
#pragma unroll
  for (int it = 0; it < 8; ++it) {
    int cl = creg[it];
    if (cl >= 0) {
      unsigned p = preg[it];
      int dl = (int)(p >> 17) - cl * CHUNK_NODES;   // 0..249 within chunk
      int r = atomicAdd(&lcur[cl], 1);
      chunk_buf[(size_t)(b * 50 + cl) * CCAP + lbase[cl] + r] =
          ((unsigned)dl << 17) | (p & 0x1FFFFu);
    }
  }
}

// ---------- exclusive scan of the 400 chunk counts ----------
__global__ __launch_bounds__(512) void k_scan_chunks(const int* __restrict__ chunk_cur,
                                                     int* __restrict__ chunk_base) {
  __shared__ int ls[512];
  const int tid = threadIdx.x;
  int v = (tid < NCHUNK) ? chunk_cur[tid] : 0;
  ls[tid] = v;
  __syncthreads();
  for (int off = 1; off < 512; off <<= 1) {
    int u = (tid >= off) ? ls[tid - off] : 0;
    __syncthreads();
    ls[tid] += u;
    __syncthreads();
  }
  if (tid < NCHUNK) chunk_base[tid] = ls[tid] - v;
}

// ---------- pass 2b: per-chunk LDS counting sort; sequential global writes ----------
__global__ __launch_bounds__(256) void k_sort_chunk(const unsigned* __restrict__ chunk_buf,
                                                    const int* __restrict__ chunk_cur,
                                                    const int* __restrict__ chunk_base,
                                                    int* __restrict__ cnt,
                                                    int* __restrict__ row_start,
                                                    int* __restrict__ sorted_src) {
  const int c    = blockIdx.x;
  const int n_c  = chunk_cur[c];
  const int base = chunk_base[c];
  const unsigned* buf = chunk_buf + (size_t)c * CCAP;
  __shared__ int cntA[256], exclA[256], curA[256];
  __shared__ int sortedL[CCAP];
  const int tid = threadIdx.x;
  cntA[tid] = 0; curA[tid] = 0;
  __syncthreads();
  for (int i = tid; i < n_c; i += 256) atomicAdd(&cntA[buf[i] >> 17], 1);
  __syncthreads();
  int myc = cntA[tid];
  exclA[tid] = myc;
  __syncthreads();
  for (int off = 1; off < 256; off <<= 1) {
    int u = (tid >= off) ? exclA[tid - off] : 0;
    __syncthreads();
    exclA[tid] += u;
    __syncthreads();
  }
  int excl = exclA[tid] - myc;
  if (tid < CHUNK_NODES) {
    int n = c * CHUNK_NODES + tid;
    cnt[n] = myc;
    row_start[n] = base + excl;
  }
  __syncthreads();
  exclA[tid] = excl;
  __syncthreads();
  for (int i = tid; i < n_c; i += 256) {
    unsigned p = buf[i];
    int dl = (int)(p >> 17);
    int pos = exclA[dl] + atomicAdd(&curA[dl], 1);
    sortedL[pos] = (int)(p & 0x1FFFFu);
  }
  __syncthreads();
  for (int i = tid; i < n_c; i += 256) sorted_src[base + i] = sortedL[i];
}

// ---------- dinv = rsqrt(deg+1) ----------
__global__ __launch_bounds__(256) void k_dinv(const int* __restrict__ cnt,
                                              float* __restrict__ dinv) {
  int i = blockIdx.x * 256 + threadIdx.x;
  if (i < N_NODES) dinv[i] = rsqrtf((float)cnt[i] + 1.0f);
}

// ---------- pad W2 (64x47) into W2p (64x48) ----------
__global__ __launch_bounds__(256) void k_padW2(const float* __restrict__ W2,
                                               float* __restrict__ W2p) {
  int i = blockIdx.x * 256 + threadIdx.x;
  if (i >= DIM_H * DIM_CP) return;
  int k = i / DIM_CP, j = i % DIM_CP;
  W2p[i] = (j < DIM_C) ? W2[k * DIM_C + j] : 0.f;
}

// ---------- pre-swizzle W1 into per-lane MFMA B-fragment order ----------
__global__ __launch_bounds__(256) void k_prepW1(const float* __restrict__ W1,
                                                short* __restrict__ W1f) {
  int i = blockIdx.x * 256 + threadIdx.x;
  if (i >= 4 * 8 * 64 * 8) return;
  int e    = i & 7;
  int lane = (i >> 3) & 63;
  int ks   = (i >> 9) & 7;
  int wv   = i >> 12;
  int col  = wv * 16 + (lane & 15);
  int k    = ks * 32 + (lane >> 4) * 8 + e;
  W1f[i] = (short)f2bf(W1[k * DIM_H + col]);
}

// ---------- layer 1 GEMM on matrix cores: h1b = bf16(dinv[n] * (x @ W1)) ----------
__global__ __launch_bounds__(256) void k_gemm1(const float* __restrict__ x,
                                               const short* __restrict__ W1f,
                                               const float* __restrict__ dinv,
                                               unsigned short* __restrict__ h1b) {
  const int lane = threadIdx.x & 63;
  const int wv   = threadIdx.x >> 6;
  const int m16  = lane & 15;
  const int kb   = lane >> 4;                 // 0..3
  const int base_row = blockIdx.x * 16;       // 100000 % 16 == 0
  const float* xp = x + (size_t)(base_row + m16) * DIM_IN + kb * 8;
  const bf16x8* wf = (const bf16x8*)W1f + (size_t)wv * 8 * 64 + lane;

  float4 a[16];
  bf16x8 b[8];
#pragma unroll
  for (int ks = 0; ks < 8; ++ks) {
    a[2 * ks]     = *(const float4*)(xp + ks * 32);
    a[2 * ks + 1] = *(const float4*)(xp + ks * 32 + 4);
    b[ks]         = wf[ks * 64];
  }
  __builtin_amdgcn_sched_barrier(0);   // keep all loads issued up front

  f32x4 c = {0.f, 0.f, 0.f, 0.f};
#pragma unroll
  for (int ks = 0; ks < 8; ++ks) {
    float4 a0 = a[2 * ks], a1 = a[2 * ks + 1];
    bf16x8 af;
    af[0] = (short)f2bf(a0.x); af[1] = (short)f2bf(a0.y);
    af[2] = (short)f2bf(a0.z); af[3] = (short)f2bf(a0.w);
    af[4] = (short)f2bf(a1.x); af[5] = (short)f2bf(a1.y);
    af[6] = (short)f2bf(a1.z); af[7] = (short)f2bf(a1.w);
    c = __builtin_amdgcn_mfma_f32_16x16x32_bf16(af, b[ks], c, 0, 0, 0);
  }

  const int j0 = wv * 16 + m16;               // output column
#pragma unroll
  for (int r = 0; r < 4; ++r) {
    int row = base_row + kb * 4 + r;
    h1b[(size_t)row * DIM_H + j0] = f2bf(c[r] * dinv[row]);
  }
}

// ---------- agg1 gather: wave per node, lane = channel, bf16 table ----------
__global__ __launch_bounds__(256) void k_agg1_gather(const unsigned short* __restrict__ h1b,
                                                     const float* __restrict__ dinv,
                                                     const float* __restrict__ b1,
                                                     const int* __restrict__ row_start,
                                                     const int* __restrict__ cnt,
                                                     const int* __restrict__ sorted_src,
                                                     float* __restrict__ agg1) {
  int n = blockIdx.x * 4 + (threadIdx.x >> 6);
  int j = threadIdx.x & 63;
  if (n >= N_NODES) return;
  int start = row_start[n];
  int deg   = cnt[n];
  float acc0 = bf2f(h1b[(size_t)n * DIM_H + j]);  // self term
  float acc1 = 0.f, acc2 = 0.f, acc3 = 0.f;
  float acc4 = 0.f, acc5 = 0.f, acc6 = 0.f, acc7 = 0.f;
  int k = 0;
  for (; k + 8 <= deg; k += 8) {
    int s0 = sorted_src[start + k + 0];
    int s1 = sorted_src[start + k + 1];
    int s2 = sorted_src[start + k + 2];
    int s3 = sorted_src[start + k + 3];
    int s4 = sorted_src[start + k + 4];
    int s5 = sorted_src[start + k + 5];
    int s6 = sorted_src[start + k + 6];
    int s7 = sorted_src[start + k + 7];
    acc0 += bf2f(h1b[(size_t)s0 * DIM_H + j]);
    acc1 += bf2f(h1b[(size_t)s1 * DIM_H + j]);
    acc2 += bf2f(h1b[(size_t)s2 * DIM_H + j]);
    acc3 += bf2f(h1b[(size_t)s3 * DIM_H + j]);
    acc4 += bf2f(h1b[(size_t)s4 * DIM_H + j]);
    acc5 += bf2f(h1b[(size_t)s5 * DIM_H + j]);
    acc6 += bf2f(h1b[(size_t)s6 * DIM_H + j]);
    acc7 += bf2f(h1b[(size_t)s7 * DIM_H + j]);
  }
  for (; k + 2 <= deg; k += 2) {
    int s0 = sorted_src[start + k + 0];
    int s1 = sorted_src[start + k + 1];
    acc0 += bf2f(h1b[(size_t)s0 * DIM_H + j]);
    acc1 += bf2f(h1b[(size_t)s1 * DIM_H + j]);
  }
  for (; k < deg; ++k)
    acc0 += bf2f(h1b[(size_t)sorted_src[start + k] * DIM_H + j]);
  float di = dinv[n];
  agg1[(size_t)n * DIM_H + j] =
      di * (((acc0 + acc1) + (acc2 + acc3)) + ((acc4 + acc5) + (acc6 + acc7))) + b1[j];
}

// ---------- layer 2 GEMM + ReLU + dinv pre-scale -> bf16 h2b ----------
__global__ __launch_bounds__(192) void k_gemm2(const float* __restrict__ agg1,
                                               const float* __restrict__ W2p,
                                               const float* __restrict__ dinv,
                                               unsigned short* __restrict__ h2b) {
  const int lane = threadIdx.x & 63;
  const int j0   = __builtin_amdgcn_readfirstlane((threadIdx.x >> 6) * 16);
  int row = blockIdx.x * 64 + lane;
  if (row >= N_NODES) row = N_NODES - 1;
  const float4* xr = (const float4*)(agg1 + (size_t)row * DIM_H);

  float4 xv[16];
#pragma unroll
  for (int k4 = 0; k4 < 16; ++k4) xv[k4] = xr[k4];
  __builtin_amdgcn_sched_barrier(0);   // all row loads in flight together

  float acc[16];
#pragma unroll
  for (int j = 0; j < 16; ++j) acc[j] = 0.f;

#pragma unroll
  for (int k4 = 0; k4 < DIM_H / 4; ++k4) {
    float4 v = xv[k4];
    v.x = fmaxf(v.x, 0.f); v.y = fmaxf(v.y, 0.f);
    v.z = fmaxf(v.z, 0.f); v.w = fmaxf(v.w, 0.f);
#pragma unroll
    for (int kk = 0; kk < 4; ++kk) {
      float xk = (kk == 0) ? v.x : (kk == 1) ? v.y : (kk == 2) ? v.z : v.w;
      const float* wrow = W2p + (size_t)(4 * k4 + kk) * DIM_CP + j0;  // uniform -> s_load
#pragma unroll
      for (int j = 0; j < 16; ++j)
        acc[j] = fmaf(xk, wrow[j], acc[j]);
    }
  }

  float di = dinv[row];
  unsigned* outp = (unsigned*)(h2b + (size_t)row * DIM_CP + j0);
#pragma unroll
  for (int p = 0; p < 8; ++p) {
    unsigned lo = f2bf(di * acc[2 * p]);
    unsigned hi = f2bf(di * acc[2 * p + 1]);
    outp[p] = lo | (hi << 16);
  }
}

// ---------- agg2 gather + fused log_softmax: bf16 table, wave per node ----------
__global__ __launch_bounds__(256) void k_agg2_gather(const unsigned short* __restrict__ h2b,
                                                     const float* __restrict__ dinv,
                                                     const float* __restrict__ b2,
                                                     const int* __restrict__ row_start,
                                                     const int* __restrict__ cnt,
                                                     const int* __restrict__ sorted_src,
                                                     float* __restrict__ out) {
  int n = blockIdx.x * 4 + (threadIdx.x >> 6);
  int j = threadIdx.x & 63;
  if (n >= N_NODES) return;
  int jj = (j < DIM_C) ? j : DIM_C;  // lanes >=47 read the zero pad
  int start = row_start[n];
  int deg   = cnt[n];
  float acc0 = bf2f(h2b[(size_t)n * DIM_CP + jj]);  // self term
  float acc1 = 0.f, acc2 = 0.f, acc3 = 0.f;
  float acc4 = 0.f, acc5 = 0.f, acc6 = 0.f, acc7 = 0.f;
  int k = 0;
  for (; k + 8 <= deg; k += 8) {
    int s0 = sorted_src[start + k + 0];
    int s1 = sorted_src[start + k + 1];
    int s2 = sorted_src[start + k + 2];
    int s3 = sorted_src[start + k + 3];
    int s4 = sorted_src[start + k + 4];
    int s5 = sorted_src[start + k + 5];
    int s6 = sorted_src[start + k + 6];
    int s7 = sorted_src[start + k + 7];
    acc0 += bf2f(h2b[(size_t)s0 * DIM_CP + jj]);
    acc1 += bf2f(h2b[(size_t)s1 * DIM_CP + jj]);
    acc2 += bf2f(h2b[(size_t)s2 * DIM_CP + jj]);
    acc3 += bf2f(h2b[(size_t)s3 * DIM_CP + jj]);
    acc4 += bf2f(h2b[(size_t)s4 * DIM_CP + jj]);
    acc5 += bf2f(h2b[(size_t)s5 * DIM_CP + jj]);
    acc6 += bf2f(h2b[(size_t)s6 * DIM_CP + jj]);
    acc7 += bf2f(h2b[(size_t)s7 * DIM_CP + jj]);
  }
  for (; k + 2 <= deg; k += 2) {
    int s0 = sorted_src[start + k + 0];
    int s1 = sorted_src[start + k + 1];
    acc0 += bf2f(h2b[(size_t)s0 * DIM_CP + jj]);
    acc1 += bf2f(h2b[(size_t)s1 * DIM_CP + jj]);
  }
  for (; k < deg; ++k)
    acc0 += bf2f(h2b[(size_t)sorted_src[start + k] * DIM_CP + jj]);
  float di = dinv[n];
  float acc = di * (((acc0 + acc1) + (acc2 + acc3)) + ((acc4 + acc5) + (acc6 + acc7)))
            + ((j < DIM_C) ? b2[jj] : 0.f);

  // fused log_softmax over the 47 classes
  float v = (j < DIM_C) ? acc : -INFINITY;
  float m = v;
  for (int o = 32; o; o >>= 1) m = fmaxf(m, __shfl_xor(m, o));
  float ex = (j < DIM_C) ? __expf(v - m) : 0.0f;
  float s = ex;
  for (int o = 32; o; o >>= 1) s += __shfl_xor(s, o);
  if (j < DIM_C) out[(size_t)n * DIM_C + j] = v - m - __logf(s);
}

extern "C" void kernel_launch(void* const* d_in, const int* in_sizes, int n_in,
                              void* d_out, int out_size, void* d_ws, size_t ws_size,
                              hipStream_t stream) {
  const float* x  = (const float*)d_in[0];
  const float* W1 = (const float*)d_in[1];
  const float* b1 = (const float*)d_in[2];
  const float* W2 = (const float*)d_in[3];
  const float* b2 = (const float*)d_in[4];
  const int*   ei = (const int*)d_in[5];
  const int* src = ei;
  const int* dst = ei + N_EDGES;
  float* out = (float*)d_out;

  float* ws   = (float*)d_ws;
  float* dinv = ws;                                   // N
  float* W2p  = dinv + N_NODES;                       // 64*48
  short* W1f  = (short*)(W2p + DIM_H * DIM_CP);       // 16384 shorts
  // h-region: max(bf16 h1b 12.8MB, chunk_buf 7.4MB, bf16 h2b 9.6MB) -> reserve 16MB/4
  unsigned short* h1b = (unsigned short*)(W1f + 4 * 8 * 64 * 8);
  float* agg1 = (float*)h1b + (size_t)N_NODES * DIM_H / 2;   // N*64 floats after 12.8MB region
  unsigned short* h2b = h1b;                          // alias: h1b dead after agg1_gather
  unsigned* chunk_buf = (unsigned*)h1b;               // alias: dead before gemm1 writes h1b
  int* ibuf        = (int*)(agg1 + (size_t)N_NODES * DIM_H);
  int* cnt         = ibuf;                            // N
  int* row_start   = cnt + N_NODES;                   // N
  int* bucket_cur  = row_start + N_NODES;             // 8 (+pad)
  int* chunk_cur   = bucket_cur + 64;                 // 400
  int* chunk_base  = chunk_cur + NCHUNK;              // 400 (+pad)
  int* sorted_src  = chunk_base + NCHUNK + 64;        // E
  unsigned* bucket_buf = (unsigned*)(sorted_src + N_EDGES);  // NB*BCAP

  const int nblk_n  = (N_NODES + 255) / 256;
  const int nblk_nw = (N_NODES + 3) / 4;              // wave-per-node gathers
  const int nblk_g1 = N_NODES / 16;                   // 6250 MFMA tiles
  const int nblk_g2 = (N_NODES + 63) / 64;            // fp32 gemm2 tiles
  const int nblk_p1 = (N_EDGES + CHUNK_P1 - 1) / CHUNK_P1;   // 1563

  // CSR build: coarse bin -> fine bin -> 400-elem scan -> per-chunk LDS sort
  k_zero<<<1, 512, 0, stream>>>(bucket_cur, chunk_cur);
  k_bin<<<nblk_p1, 256, 0, stream>>>(src, dst, bucket_cur, bucket_buf);
  k_bin2<<<NB * NSEG_P2, 256, 0, stream>>>(bucket_buf, bucket_cur, chunk_cur, chunk_buf);
  k_scan_chunks<<<1, 512, 0, stream>>>(chunk_cur, chunk_base);
  k_sort_chunk<<<NCHUNK, 256, 0, stream>>>(chunk_buf, chunk_cur, chunk_base,
                                           cnt, row_start, sorted_src);
  k_dinv<<<nblk_n, 256, 0, stream>>>(cnt, dinv);
  k_padW2<<<(DIM_H * DIM_CP + 255) / 256, 256, 0, stream>>>(W2, W2p);
  k_prepW1<<<64, 256, 0, stream>>>(W1, W1f);

  // layer 1 (MFMA, bf16 output)
  k_gemm1<<<nblk_g1, 256, 0, stream>>>(x, W1f, dinv, h1b);
  k_agg1_gather<<<nblk_nw, 256, 0, stream>>>(h1b, dinv, b1, row_start, cnt, sorted_src, agg1);

  // layer 2 (+ fused log_softmax), bf16 intermediate
  k_gemm2<<<nblk_g2, 192, 0, stream>>>(agg1, W2p, dinv, h2b);
  k_agg2_gather<<<nblk_nw, 256, 0, stream>>>(h2b, dinv, b2, row_start, cnt, sorted_src, out);
}

// Round 14
// 244.267 us; speedup vs baseline: 1.5447x; 1.0804x over previous
//
#include <hip/hip_runtime.h>
#include <math.h>

#define N_NODES 100000
#define N_EDGES 1600000
#define DIM_IN  256
#define DIM_H   64
#define DIM_C   47
#define DIM_CP  48                            // padded h2 row stride (96B bf16)
#define NB       8                            // coarse dst buckets
#define BUCKET_W 12500                        // nodes per bucket
#define BCAP     204000                       // per-bucket capacity (9.5 sigma)
#define CHUNK_P1 1024                         // edges per pass-1 block (4/thread)
#define SEG_P2   2048                         // bucket-buf segment per pass-2a block
#define NSEG_P2  100                          // segments per bucket
#define CHUNK_NODES 250                       // nodes per fine chunk
#define NCHUNK   400                          // N_NODES / 250
#define CCAP     4608                         // per-chunk edge capacity
#define XPAD     260                          // x-tile row stride in floats (+4 bank rotate)

typedef __attribute__((ext_vector_type(8))) short bf16x8;
typedef __attribute__((ext_vector_type(4))) float f32x4;

// RNE float -> bf16 bits
static __device__ __forceinline__ unsigned short f2bf(float f) {
  unsigned u = __builtin_bit_cast(unsigned, f);
  u += 0x7FFFu + ((u >> 16) & 1u);
  return (unsigned short)(u >> 16);
}
static __device__ __forceinline__ float bf2f(unsigned short h) {
  unsigned u = ((unsigned)h) << 16;
  return __builtin_bit_cast(float, u);
}

// ---------- zero the counters ----------
__global__ __launch_bounds__(512) void k_zero(int* __restrict__ bucket_cur,
                                              int* __restrict__ chunk_cur) {
  if (threadIdx.x < NB) bucket_cur[threadIdx.x] = 0;
  if (threadIdx.x < NCHUNK) chunk_cur[threadIdx.x] = 0;
}

// ---------- pass 1: coarse octant binning (dense reservation writes) ----------
__global__ __launch_bounds__(256) void k_bin(const int* __restrict__ src,
                                             const int* __restrict__ dst,
                                             int* __restrict__ bucket_cur,
                                             unsigned* __restrict__ bucket_buf) {
  __shared__ int lcnt[NB], lbase[NB], lcur[NB];
  if (threadIdx.x < NB) lcnt[threadIdx.x] = 0;
  __syncthreads();
  const int base = blockIdx.x * CHUNK_P1 + threadIdx.x;
  int dreg[4], sreg[4];
#pragma unroll
  for (int it = 0; it < 4; ++it) {
    int e = base + it * 256;
    int d = -1, s = 0;
    if (e < N_EDGES) { d = dst[e]; s = src[e]; }
    dreg[it] = d; sreg[it] = s;
    if (d >= 0) atomicAdd(&lcnt[d / BUCKET_W], 1);
  }
  __syncthreads();
  if (threadIdx.x < NB) {
    lbase[threadIdx.x] = atomicAdd(&bucket_cur[threadIdx.x], lcnt[threadIdx.x]);
    lcur[threadIdx.x] = 0;
  }
  __syncthreads();
#pragma unroll
  for (int it = 0; it < 4; ++it) {
    int d = dreg[it];
    if (d >= 0) {
      int b = d / BUCKET_W;
      int r = atomicAdd(&lcur[b], 1);
      unsigned pack = ((unsigned)(d - b * BUCKET_W) << 17) | (unsigned)sreg[it];
      bucket_buf[(size_t)b * BCAP + lbase[b] + r] = pack;
    }
  }
}

// ---------- pass 2a: bucket -> 50 fine chunks (dense reservation writes) ----------
__global__ __launch_bounds__(256) void k_bin2(const unsigned* __restrict__ bucket_buf,
                                              const int* __restrict__ bucket_cnt,
                                              int* __restrict__ chunk_cur,
                                              unsigned* __restrict__ chunk_buf) {
  const int b   = blockIdx.x / NSEG_P2;
  const int seg = blockIdx.x % NSEG_P2;
  const int n_b = bucket_cnt[b];
  const int s0  = seg * SEG_P2;
  const int s1  = (n_b < s0 + SEG_P2) ? n_b : (s0 + SEG_P2);
  __shared__ int lcnt[50], lbase[50], lcur[50];
  if (threadIdx.x < 50) lcnt[threadIdx.x] = 0;
  __syncthreads();
  unsigned preg[8]; int creg[8];
#pragma unroll
  for (int it = 0; it < 8; ++it) {
    int i = s0 + it * 256 + (int)threadIdx.x;
    unsigned p = 0; int cl = -1;
    if (i < s1) { p = bucket_buf[(size_t)b * BCAP + i]; cl = (int)(p >> 17) / CHUNK_NODES; atomicAdd(&lcnt[cl], 1); }
    preg[it] = p; creg[it] = cl;
  }
  __syncthreads();
  if (threadIdx.x < 50) {
    lbase[threadIdx.x] = atomicAdd(&chunk_cur[b * 50 + threadIdx.x], lcnt[threadIdx.x]);
    lcur[threadIdx.x] = 0;
  }
  __syncthreads();
#pragma unroll
  for (int it = 0; it < 8; ++it) {
    int cl = creg[it];
    if (cl >= 0) {
      unsigned p = preg[it];
      int dl = (int)(p >> 17) - cl * CHUNK_NODES;   // 0..249 within chunk
      int r = atomicAdd(&lcur[cl], 1);
      chunk_buf[(size_t)(b * 50 + cl) * CCAP + lbase[cl] + r] =
          ((unsigned)dl << 17) | (p & 0x1FFFFu);
    }
  }
}

// ---------- exclusive scan of the 400 chunk counts ----------
__global__ __launch_bounds__(512) void k_scan_chunks(const int* __restrict__ chunk_cur,
                                                     int* __restrict__ chunk_base) {
  __shared__ int ls[512];
  const int tid = threadIdx.x;
  int v = (tid < NCHUNK) ? chunk_cur[tid] : 0;
  ls[tid] = v;
  __syncthreads();
  for (int off = 1; off < 512; off <<= 1) {
    int u = (tid >= off) ? ls[tid - off] : 0;
    __syncthreads();
    ls[tid] += u;
    __syncthreads();
  }
  if (tid < NCHUNK) chunk_base[tid] = ls[tid] - v;
}

// ---------- pass 2b: per-chunk LDS counting sort; sequential global writes ----------
__global__ __launch_bounds__(256) void k_sort_chunk(const unsigned* __restrict__ chunk_buf,
                                                    const int* __restrict__ chunk_cur,
                                                    const int* __restrict__ chunk_base,
                                                    int* __restrict__ cnt,
                                                    int* __restrict__ row_start,
                                                    int* __restrict__ sorted_src) {
  const int c    = blockIdx.x;
  const int n_c  = chunk_cur[c];
  const int base = chunk_base[c];
  const unsigned* buf = chunk_buf + (size_t)c * CCAP;
  __shared__ int cntA[256], exclA[256], curA[256];
  __shared__ int sortedL[CCAP];
  const int tid = threadIdx.x;
  cntA[tid] = 0; curA[tid] = 0;
  __syncthreads();
  for (int i = tid; i < n_c; i += 256) atomicAdd(&cntA[buf[i] >> 17], 1);
  __syncthreads();
  int myc = cntA[tid];
  exclA[tid] = myc;
  __syncthreads();
  for (int off = 1; off < 256; off <<= 1) {
    int u = (tid >= off) ? exclA[tid - off] : 0;
    __syncthreads();
    exclA[tid] += u;
    __syncthreads();
  }
  int excl = exclA[tid] - myc;
  if (tid < CHUNK_NODES) {
    int n = c * CHUNK_NODES + tid;
    cnt[n] = myc;
    row_start[n] = base + excl;
  }
  __syncthreads();
  exclA[tid] = excl;
  __syncthreads();
  for (int i = tid; i < n_c; i += 256) {
    unsigned p = buf[i];
    int dl = (int)(p >> 17);
    int pos = exclA[dl] + atomicAdd(&curA[dl], 1);
    sortedL[pos] = (int)(p & 0x1FFFFu);
  }
  __syncthreads();
  for (int i = tid; i < n_c; i += 256) sorted_src[base + i] = sortedL[i];
}

// ---------- dinv = rsqrt(deg+1) ----------
__global__ __launch_bounds__(256) void k_dinv(const int* __restrict__ cnt,
                                              float* __restrict__ dinv) {
  int i = blockIdx.x * 256 + threadIdx.x;
  if (i < N_NODES) dinv[i] = rsqrtf((float)cnt[i] + 1.0f);
}

// ---------- pad W2 (64x47) into W2p (64x48) ----------
__global__ __launch_bounds__(256) void k_padW2(const float* __restrict__ W2,
                                               float* __restrict__ W2p) {
  int i = blockIdx.x * 256 + threadIdx.x;
  if (i >= DIM_H * DIM_CP) return;
  int k = i / DIM_CP, j = i % DIM_CP;
  W2p[i] = (j < DIM_C) ? W2[k * DIM_C + j] : 0.f;
}

// ---------- pre-swizzle W1 into per-lane MFMA B-fragment order ----------
__global__ __launch_bounds__(256) void k_prepW1(const float* __restrict__ W1,
                                                short* __restrict__ W1f) {
  int i = blockIdx.x * 256 + threadIdx.x;
  if (i >= 4 * 8 * 64 * 8) return;
  int e    = i & 7;
  int lane = (i >> 3) & 63;
  int ks   = (i >> 9) & 7;
  int wv   = i >> 12;
  int col  = wv * 16 + (lane & 15);
  int k    = ks * 32 + (lane >> 4) * 8 + e;
  W1f[i] = (short)f2bf(W1[k * DIM_H + col]);
}

// ---------- layer 1 GEMM on matrix cores: h1b = bf16(dinv[n] * (x @ W1)) ----------
// 64-row x-tile staged via async global_load_lds (width 16) -> LDS [64][260] fp32.
// DMA has no dest VGPRs so the compiler can't sink it (R12/R13: batched VGPR
// loads kept getting re-serialized, VGPR=32, MfmaUtil 1.9%). One barrier drains
// vmcnt, then each wave runs 4 row-groups x 8 k-steps of 16x16x32 MFMA.
__global__ __launch_bounds__(256) void k_gemm1(const float* __restrict__ x,
                                               const short* __restrict__ W1f,
                                               const float* __restrict__ dinv,
                                               unsigned short* __restrict__ h1b) {
  __shared__ float xt[64][XPAD];              // 66560B -> 2 blocks/CU
  const int lane = threadIdx.x & 63;
  const int wv   = threadIdx.x >> 6;
  const int m16  = lane & 15;
  const int kb   = lane >> 4;                 // 0..3
  const int base_row = blockIdx.x * 64;

  // stage: one instruction = one full 1KB row (64 lanes x 16B), rows interleaved by wave
#pragma unroll
  for (int i = 0; i < 16; ++i) {
    int r = i * 4 + wv;                       // wave-uniform row
    int grow = base_row + r;
    if (grow >= N_NODES) grow = N_NODES - 1;  // tail: duplicate last row, stores guarded
    const float* g = x + (size_t)grow * DIM_IN + lane * 4;
    __builtin_amdgcn_global_load_lds((const __attribute__((address_space(1))) void*)g,
                                     (__attribute__((address_space(3))) void*)&xt[r][0],
                                     16, 0, 0);
  }
  __syncthreads();                            // drains vmcnt(0) + barrier

  const bf16x8* wf = (const bf16x8*)W1f + (size_t)wv * 8 * 64 + lane;
  f32x4 c0 = {0.f, 0.f, 0.f, 0.f}, c1 = c0, c2 = c0, c3 = c0;
#pragma unroll
  for (int ks = 0; ks < 8; ++ks) {
    bf16x8 bb = wf[ks * 64];
#pragma unroll
    for (int rg = 0; rg < 4; ++rg) {
      const float* xr = &xt[rg * 16 + m16][kb * 8 + ks * 32];
      float4 a0 = *(const float4*)xr;
      float4 a1 = *(const float4*)(xr + 4);
      bf16x8 af;
      af[0] = (short)f2bf(a0.x); af[1] = (short)f2bf(a0.y);
      af[2] = (short)f2bf(a0.z); af[3] = (short)f2bf(a0.w);
      af[4] = (short)f2bf(a1.x); af[5] = (short)f2bf(a1.y);
      af[6] = (short)f2bf(a1.z); af[7] = (short)f2bf(a1.w);
      if (rg == 0) c0 = __builtin_amdgcn_mfma_f32_16x16x32_bf16(af, bb, c0, 0, 0, 0);
      if (rg == 1) c1 = __builtin_amdgcn_mfma_f32_16x16x32_bf16(af, bb, c1, 0, 0, 0);
      if (rg == 2) c2 = __builtin_amdgcn_mfma_f32_16x16x32_bf16(af, bb, c2, 0, 0, 0);
      if (rg == 3) c3 = __builtin_amdgcn_mfma_f32_16x16x32_bf16(af, bb, c3, 0, 0, 0);
    }
  }

  const int j0 = wv * 16 + m16;               // output column
#pragma unroll
  for (int rg = 0; rg < 4; ++rg) {
    f32x4 c = (rg == 0) ? c0 : (rg == 1) ? c1 : (rg == 2) ? c2 : c3;
#pragma unroll
    for (int r = 0; r < 4; ++r) {
      int row = base_row + rg * 16 + kb * 4 + r;
      if (row < N_NODES) h1b[(size_t)row * DIM_H + j0] = f2bf(c[r] * dinv[row]);
    }
  }
}

// ---------- agg1 gather: wave per node, lane = channel, bf16 table ----------
__global__ __launch_bounds__(256) void k_agg1_gather(const unsigned short* __restrict__ h1b,
                                                     const float* __restrict__ dinv,
                                                     const float* __restrict__ b1,
                                                     const int* __restrict__ row_start,
                                                     const int* __restrict__ cnt,
                                                     const int* __restrict__ sorted_src,
                                                     float* __restrict__ agg1) {
  int n = blockIdx.x * 4 + (threadIdx.x >> 6);
  int j = threadIdx.x & 63;
  if (n >= N_NODES) return;
  int start = row_start[n];
  int deg   = cnt[n];
  float acc0 = bf2f(h1b[(size_t)n * DIM_H + j]);  // self term
  float acc1 = 0.f, acc2 = 0.f, acc3 = 0.f;
  float acc4 = 0.f, acc5 = 0.f, acc6 = 0.f, acc7 = 0.f;
  int k = 0;
  for (; k + 8 <= deg; k += 8) {
    int s0 = sorted_src[start + k + 0];
    int s1 = sorted_src[start + k + 1];
    int s2 = sorted_src[start + k + 2];
    int s3 = sorted_src[start + k + 3];
    int s4 = sorted_src[start + k + 4];
    int s5 = sorted_src[start + k + 5];
    int s6 = sorted_src[start + k + 6];
    int s7 = sorted_src[start + k + 7];
    acc0 += bf2f(h1b[(size_t)s0 * DIM_H + j]);
    acc1 += bf2f(h1b[(size_t)s1 * DIM_H + j]);
    acc2 += bf2f(h1b[(size_t)s2 * DIM_H + j]);
    acc3 += bf2f(h1b[(size_t)s3 * DIM_H + j]);
    acc4 += bf2f(h1b[(size_t)s4 * DIM_H + j]);
    acc5 += bf2f(h1b[(size_t)s5 * DIM_H + j]);
    acc6 += bf2f(h1b[(size_t)s6 * DIM_H + j]);
    acc7 += bf2f(h1b[(size_t)s7 * DIM_H + j]);
  }
  for (; k + 2 <= deg; k += 2) {
    int s0 = sorted_src[start + k + 0];
    int s1 = sorted_src[start + k + 1];
    acc0 += bf2f(h1b[(size_t)s0 * DIM_H + j]);
    acc1 += bf2f(h1b[(size_t)s1 * DIM_H + j]);
  }
  for (; k < deg; ++k)
    acc0 += bf2f(h1b[(size_t)sorted_src[start + k] * DIM_H + j]);
  float di = dinv[n];
  agg1[(size_t)n * DIM_H + j] =
      di * (((acc0 + acc1) + (acc2 + acc3)) + ((acc4 + acc5) + (acc6 + acc7))) + b1[j];
}

// ---------- layer 2 GEMM + ReLU + dinv pre-scale -> bf16 h2b ----------
__global__ __launch_bounds__(192) void k_gemm2(const float* __restrict__ agg1,
                                               const float* __restrict__ W2p,
                                               const float* __restrict__ dinv,
                                               unsigned short* __restrict__ h2b) {
  const int lane = threadIdx.x & 63;
  const int j0   = __builtin_amdgcn_readfirstlane((threadIdx.x >> 6) * 16);
  int row = blockIdx.x * 64 + lane;
  if (row >= N_NODES) row = N_NODES - 1;
  const float4* xr = (const float4*)(agg1 + (size_t)row * DIM_H);

  float4 xv[16];
#pragma unroll
  for (int k4 = 0; k4 < 16; ++k4) xv[k4] = xr[k4];
  __builtin_amdgcn_sched_barrier(0);

  float acc[16];
#pragma unroll
  for (int j = 0; j < 16; ++j) acc[j] = 0.f;

#pragma unroll
  for (int k4 = 0; k4 < DIM_H / 4; ++k4) {
    float4 v = xv[k4];
    v.x = fmaxf(v.x, 0.f); v.y = fmaxf(v.y, 0.f);
    v.z = fmaxf(v.z, 0.f); v.w = fmaxf(v.w, 0.f);
#pragma unroll
    for (int kk = 0; kk < 4; ++kk) {
      float xk = (kk == 0) ? v.x : (kk == 1) ? v.y : (kk == 2) ? v.z : v.w;
      const float* wrow = W2p + (size_t)(4 * k4 + kk) * DIM_CP + j0;  // uniform -> s_load
#pragma unroll
      for (int j = 0; j < 16; ++j)
        acc[j] = fmaf(xk, wrow[j], acc[j]);
    }
  }

  float di = dinv[row];
  unsigned* outp = (unsigned*)(h2b + (size_t)row * DIM_CP + j0);
#pragma unroll
  for (int p = 0; p < 8; ++p) {
    unsigned lo = f2bf(di * acc[2 * p]);
    unsigned hi = f2bf(di * acc[2 * p + 1]);
    outp[p] = lo | (hi << 16);
  }
}

// ---------- agg2 gather + fused log_softmax: bf16 table, wave per node ----------
__global__ __launch_bounds__(256) void k_agg2_gather(const unsigned short* __restrict__ h2b,
                                                     const float* __restrict__ dinv,
                                                     const float* __restrict__ b2,
                                                     const int* __restrict__ row_start,
                                                     const int* __restrict__ cnt,
                                                     const int* __restrict__ sorted_src,
                                                     float* __restrict__ out) {
  int n = blockIdx.x * 4 + (threadIdx.x >> 6);
  int j = threadIdx.x & 63;
  if (n >= N_NODES) return;
  int jj = (j < DIM_C) ? j : DIM_C;  // lanes >=47 read the zero pad
  int start = row_start[n];
  int deg   = cnt[n];
  float acc0 = bf2f(h2b[(size_t)n * DIM_CP + jj]);  // self term
  float acc1 = 0.f, acc2 = 0.f, acc3 = 0.f;
  float acc4 = 0.f, acc5 = 0.f, acc6 = 0.f, acc7 = 0.f;
  int k = 0;
  for (; k + 8 <= deg; k += 8) {
    int s0 = sorted_src[start + k + 0];
    int s1 = sorted_src[start + k + 1];
    int s2 = sorted_src[start + k + 2];
    int s3 = sorted_src[start + k + 3];
    int s4 = sorted_src[start + k + 4];
    int s5 = sorted_src[start + k + 5];
    int s6 = sorted_src[start + k + 6];
    int s7 = sorted_src[start + k + 7];
    acc0 += bf2f(h2b[(size_t)s0 * DIM_CP + jj]);
    acc1 += bf2f(h2b[(size_t)s1 * DIM_CP + jj]);
    acc2 += bf2f(h2b[(size_t)s2 * DIM_CP + jj]);
    acc3 += bf2f(h2b[(size_t)s3 * DIM_CP + jj]);
    acc4 += bf2f(h2b[(size_t)s4 * DIM_CP + jj]);
    acc5 += bf2f(h2b[(size_t)s5 * DIM_CP + jj]);
    acc6 += bf2f(h2b[(size_t)s6 * DIM_CP + jj]);
    acc7 += bf2f(h2b[(size_t)s7 * DIM_CP + jj]);
  }
  for (; k + 2 <= deg; k += 2) {
    int s0 = sorted_src[start + k + 0];
    int s1 = sorted_src[start + k + 1];
    acc0 += bf2f(h2b[(size_t)s0 * DIM_CP + jj]);
    acc1 += bf2f(h2b[(size_t)s1 * DIM_CP + jj]);
  }
  for (; k < deg; ++k)
    acc0 += bf2f(h2b[(size_t)sorted_src[start + k] * DIM_CP + jj]);
  float di = dinv[n];
  float acc = di * (((acc0 + acc1) + (acc2 + acc3)) + ((acc4 + acc5) + (acc6 + acc7)))
            + ((j < DIM_C) ? b2[jj] : 0.f);

  // fused log_softmax over the 47 classes
  float v = (j < DIM_C) ? acc : -INFINITY;
  float m = v;
  for (int o = 32; o; o >>= 1) m = fmaxf(m, __shfl_xor(m, o));
  float ex = (j < DIM_C) ? __expf(v - m) : 0.0f;
  float s = ex;
  for (int o = 32; o; o >>= 1) s += __shfl_xor(s, o);
  if (j < DIM_C) out[(size_t)n * DIM_C + j] = v - m - __logf(s);
}

extern "C" void kernel_launch(void* const* d_in, const int* in_sizes, int n_in,
                              void* d_out, int out_size, void* d_ws, size_t ws_size,
                              hipStream_t stream) {
  const float* x  = (const float*)d_in[0];
  const float* W1 = (const float*)d_in[1];
  const float* b1 = (const float*)d_in[2];
  const float* W2 = (const float*)d_in[3];
  const float* b2 = (const float*)d_in[4];
  const int*   ei = (const int*)d_in[5];
  const int* src = ei;
  const int* dst = ei + N_EDGES;
  float* out = (float*)d_out;

  float* ws   = (float*)d_ws;
  float* dinv = ws;                                   // N
  float* W2p  = dinv + N_NODES;                       // 64*48
  short* W1f  = (short*)(W2p + DIM_H * DIM_CP);       // 16384 shorts
  unsigned short* h1b = (unsigned short*)(W1f + 4 * 8 * 64 * 8);   // N*64 bf16 (12.8MB)
  float* agg1 = (float*)h1b + (size_t)N_NODES * DIM_H / 2;         // N*64 f32
  unsigned short* h2b = h1b;                          // alias: h1b dead after agg1_gather
  unsigned* chunk_buf = (unsigned*)h1b;               // alias: dead before gemm1 writes h1b
  int* ibuf        = (int*)(agg1 + (size_t)N_NODES * DIM_H);
  int* cnt         = ibuf;                            // N
  int* row_start   = cnt + N_NODES;                   // N
  int* bucket_cur  = row_start + N_NODES;             // 8 (+pad)
  int* chunk_cur   = bucket_cur + 64;                 // 400
  int* chunk_base  = chunk_cur + NCHUNK;              // 400 (+pad)
  int* sorted_src  = chunk_base + NCHUNK + 64;        // E
  unsigned* bucket_buf = (unsigned*)(sorted_src + N_EDGES);  // NB*BCAP

  const int nblk_n  = (N_NODES + 255) / 256;
  const int nblk_nw = (N_NODES + 3) / 4;              // wave-per-node gathers
  const int nblk_g1 = (N_NODES + 63) / 64;            // 64-row MFMA tiles
  const int nblk_g2 = (N_NODES + 63) / 64;            // fp32 gemm2 tiles
  const int nblk_p1 = (N_EDGES + CHUNK_P1 - 1) / CHUNK_P1;   // 1563

  // CSR build: coarse bin -> fine bin -> 400-elem scan -> per-chunk LDS sort
  k_zero<<<1, 512, 0, stream>>>(bucket_cur, chunk_cur);
  k_bin<<<nblk_p1, 256, 0, stream>>>(src, dst, bucket_cur, bucket_buf);
  k_bin2<<<NB * NSEG_P2, 256, 0, stream>>>(bucket_buf, bucket_cur, chunk_cur, chunk_buf);
  k_scan_chunks<<<1, 512, 0, stream>>>(chunk_cur, chunk_base);
  k_sort_chunk<<<NCHUNK, 256, 0, stream>>>(chunk_buf, chunk_cur, chunk_base,
                                           cnt, row_start, sorted_src);
  k_dinv<<<nblk_n, 256, 0, stream>>>(cnt, dinv);
  k_padW2<<<(DIM_H * DIM_CP + 255) / 256, 256, 0, stream>>>(W2, W2p);
  k_prepW1<<<64, 256, 0, stream>>>(W1, W1f);

  // layer 1 (MFMA, async LDS-staged x, bf16 output)
  k_gemm1<<<nblk_g1, 256, 0, stream>>>(x, W1f, dinv, h1b);
  k_agg1_gather<<<nblk_nw, 256, 0, stream>>>(h1b, dinv, b1, row_start, cnt, sorted_src, agg1);

  // layer 2 (+ fused log_softmax), bf16 intermediate
  k_gemm2<<<nblk_g2, 192, 0, stream>>>(agg1, W2p, dinv, h2b);
  k_agg2_gather<<<nblk_nw, 256, 0, stream>>>(h2b, dinv, b2, row_start, cnt, sorted_src, out);
}